// Round 3
// baseline (226.662 us; speedup 1.0000x reference)
//
#include <hip/hip_runtime.h>
#include <stdint.h>

typedef unsigned short u16;
typedef unsigned int u32;

#define N_NODES 2708
#define IN_C    2048
#define OUT_C   512
#define MP      2816   // padded node count (multiple of 128)
#define KP      2816   // padded K for gemm2 (= MP)

using floatx4 = __attribute__((ext_vector_type(4))) float;
using short8  = __attribute__((ext_vector_type(8))) short;

// ---- workspace layout (38.1 MB total) ----
constexpr size_t XB_OFF  = 0;
constexpr size_t XB_SZ   = (size_t)MP * IN_C * 2;      // 11,534,336
constexpr size_t WB_OFF  = XB_OFF + XB_SZ;
constexpr size_t WB_SZ   = (size_t)OUT_C * IN_C * 2;   //  2,097,152
constexpr size_t HT_OFF  = WB_OFF + WB_SZ;
constexpr size_t HT_SZ   = (size_t)OUT_C * MP * 2;     //  2,883,584
constexpr size_t HTF_OFF = HT_OFF + HT_SZ;
constexpr size_t HTF_SZ  = (size_t)OUT_C * MP * 4;     //  5,767,168
constexpr size_t AC_OFF  = HTF_OFF + HTF_SZ;
constexpr size_t AC_SZ   = (size_t)MP * KP * 2;        // 15,859,712

static __device__ __forceinline__ u16 f2bf(float f) {
  union { float f; u32 u; } v; v.f = f;
  u32 r = v.u + 0x7fffu + ((v.u >> 16) & 1u);  // RNE
  return (u16)(r >> 16);
}

// ---- fused prep: convert x -> bf16 (padded), w -> bf16, zero hTf+Ac+out ----
constexpr int XBLK = MP * IN_C / 8 / 256;              // 2816 (block b == row b)
constexpr int WBLK = OUT_C * IN_C / 8 / 256;           // 512
constexpr int Z1F4 = (int)((HTF_SZ + AC_SZ) / 16);     // 1,351,680 (hTf+Ac contiguous)
constexpr int Z2F4 = N_NODES * OUT_C * 4 / 16;         // 346,624
constexpr int ZBLK = (Z1F4 + Z2F4) / 256;              // 6634 (exact)
constexpr int PREP_BLK = XBLK + WBLK + ZBLK;           // 9962

__global__ void k_prep(const float* __restrict__ x, const float* __restrict__ w,
                       u16* __restrict__ xb, u16* __restrict__ wb,
                       float4* __restrict__ z1, float4* __restrict__ z2) {
  const int b = blockIdx.x, tid = threadIdx.x;
  if (b < XBLK) {
    const int row = b, col = tid * 8;
    union { u16 u[8]; uint4 v; } o;
    if (row < N_NODES) {
      float4 v0 = *(const float4*)&x[(size_t)row * IN_C + col];
      float4 v1 = *(const float4*)&x[(size_t)row * IN_C + col + 4];
      o.u[0]=f2bf(v0.x); o.u[1]=f2bf(v0.y); o.u[2]=f2bf(v0.z); o.u[3]=f2bf(v0.w);
      o.u[4]=f2bf(v1.x); o.u[5]=f2bf(v1.y); o.u[6]=f2bf(v1.z); o.u[7]=f2bf(v1.w);
    } else {
      o.v = make_uint4(0, 0, 0, 0);
    }
    *(uint4*)&xb[(size_t)row * IN_C + col] = o.v;
  } else if (b < XBLK + WBLK) {
    const int idx = ((b - XBLK) * 256 + tid) * 8;
    float4 v0 = *(const float4*)&w[idx];
    float4 v1 = *(const float4*)&w[idx + 4];
    union { u16 u[8]; uint4 v; } o;
    o.u[0]=f2bf(v0.x); o.u[1]=f2bf(v0.y); o.u[2]=f2bf(v0.z); o.u[3]=f2bf(v0.w);
    o.u[4]=f2bf(v1.x); o.u[5]=f2bf(v1.y); o.u[6]=f2bf(v1.z); o.u[7]=f2bf(v1.w);
    *(uint4*)&wb[idx] = o.v;
  } else {
    const int i = (b - XBLK - WBLK) * 256 + tid;
    const float4 z = make_float4(0.f, 0.f, 0.f, 0.f);
    if (i < Z1F4) z1[i] = z;
    else          z2[i - Z1F4] = z;
  }
}

// ---- edge counts into u16 halfwords via u32 atomics ----
__global__ void k_count(const int* __restrict__ ei, u32* __restrict__ Ac, int E) {
  int e = blockIdx.x * 256 + threadIdx.x;
  if (e < E) {
    int src = ei[e];
    int dst = ei[E + e];
    u32 idx = (u32)dst * KP + (u32)src;  // u16 element index
    atomicAdd(&Ac[idx >> 1], 1u << ((idx & 1) * 16));
  }
}

// ---- in-place u16 count -> bf16 (exact for counts <= 256) ----
static __device__ __forceinline__ u32 cvt2(u32 w) {
  float lo = (float)(w & 0xffffu), hi = (float)(w >> 16);
  return (u32)f2bf(lo) | ((u32)f2bf(hi) << 16);
}
__global__ void k_cvtA(uint4* __restrict__ A, int n) {
  int i = blockIdx.x * 256 + threadIdx.x;
  if (i < n) {
    uint4 v = A[i];
    A[i] = make_uint4(cvt2(v.x), cvt2(v.y), cvt2(v.z), cvt2(v.w));
  }
}

// ---- hTf (f32, K-split partials) + bias -> hT bf16 [OUT_C][MP] ----
__global__ void k_biascvt(const float* __restrict__ hTf, const float* __restrict__ bias,
                          u16* __restrict__ hT) {
  int i8 = blockIdx.x * 256 + threadIdx.x;       // [0, OUT_C * MP/8)
  int n = i8 / (MP / 8);
  int m0 = (i8 - n * (MP / 8)) * 8;
  float bv = bias[n];
  const float* p = &hTf[(size_t)n * MP + m0];
  float4 v0 = *(const float4*)p;
  float4 v1 = *(const float4*)(p + 4);
  union { u16 u[8]; uint4 v; } o;
  o.u[0]=f2bf(v0.x+bv); o.u[1]=f2bf(v0.y+bv); o.u[2]=f2bf(v0.z+bv); o.u[3]=f2bf(v0.w+bv);
  o.u[4]=f2bf(v1.x+bv); o.u[5]=f2bf(v1.y+bv); o.u[6]=f2bf(v1.z+bv); o.u[7]=f2bf(v1.w+bv);
  *(uint4*)&hT[(size_t)n * MP + m0] = o.v;
}

// ---- GEMM: C[m][n] (+)= sum_k A[m][k]*B[n][k], both bf16 row-major ld=LDK.
// BM=128 BN=64 BK=64, 4 waves 2x2, double-buffered global_load_lds (T3-min 2-phase).
// Grid = 8(bn) * 22(bm) * KSPLIT, XCD-bijective swizzle so the 8 bn-sharers of an
// A-panel land on one XCD (panel fetched once into that XCD's L2).
// EPI=0: atomicAdd dst[n*MP+m] (hTf);  EPI=1: atomicAdd dst[m*OUT_C+n], m<N_NODES.
template<int LDK, int NKI, int EPI>
__global__ __launch_bounds__(256, 3) void k_gemm(
    const u16* __restrict__ A, const u16* __restrict__ B, float* __restrict__ dst) {
  __shared__ u16 lA[2][128 * 64];
  __shared__ u16 lB[2][64 * 64];
  const int tid = threadIdx.x, lane = tid & 63, wid = tid >> 6;

  // XCD swizzle (m157; gridDim.x % 8 == 0 -> bijective)
  const int cpx = (int)gridDim.x >> 3;
  const int orig = blockIdx.x;
  const int swz = (orig & 7) * cpx + (orig >> 3);
  const int bn = swz & 7, panel = swz >> 3;
  const int ks = panel / 22, bm = panel - ks * 22;
  const int bmr = bm * 128, bnr = bn * 64;
  const long k0b = (long)ks * NKI * 128;   // K base in bytes (NKI*64 elems * 2B)

  const int wr = wid >> 1, wc = wid & 1;

  // per-lane global source pointers: chunk c covers LDS bytes [1024c,1024c+1024)
  // = tile rows [8c, 8c+8); lane l -> row 8c+(l>>3), col byte (l&7)*16
  const char* ag[4];
  const char* bg[2];
#pragma unroll
  for (int j = 0; j < 4; ++j) {
    int c = wid + 4 * j, row = 8 * c + (lane >> 3);
    ag[j] = (const char*)A + (size_t)(bmr + row) * (LDK * 2) + k0b + (lane & 7) * 16;
  }
#pragma unroll
  for (int j = 0; j < 2; ++j) {
    int c = wid + 4 * j, row = 8 * c + (lane >> 3);
    bg[j] = (const char*)B + (size_t)(bnr + row) * (LDK * 2) + k0b + (lane & 7) * 16;
  }

#define STAGE(bb, tt) do {                                                        \
  _Pragma("unroll")                                                               \
  for (int j = 0; j < 4; ++j)                                                     \
    __builtin_amdgcn_global_load_lds(                                             \
      (const __attribute__((address_space(1))) u32*)(ag[j] + (size_t)(tt) * 128), \
      (__attribute__((address_space(3))) u32*)&lA[bb][(wid + 4 * j) * 512],       \
      16, 0, 0);                                                                  \
  _Pragma("unroll")                                                               \
  for (int j = 0; j < 2; ++j)                                                     \
    __builtin_amdgcn_global_load_lds(                                             \
      (const __attribute__((address_space(1))) u32*)(bg[j] + (size_t)(tt) * 128), \
      (__attribute__((address_space(3))) u32*)&lB[bb][(wid + 4 * j) * 512],       \
      16, 0, 0);                                                                  \
} while (0)

  floatx4 acc[4][2] = {};

  STAGE(0, 0);
  int cur = 0;
  for (int t = 0; t < NKI; ++t) {
    __syncthreads();                       // stage(t) landed (vmcnt0+lgkm0+barrier)
    if (t + 1 < NKI) STAGE(cur ^ 1, t + 1);  // prefetch overlaps with MFMA below
    const u16* pA = lA[cur];
    const u16* pB = lB[cur];
    short8 af[4][2], bf[2][2];
#pragma unroll
    for (int mi = 0; mi < 4; ++mi)
#pragma unroll
      for (int kk = 0; kk < 2; ++kk)
        af[mi][kk] = *(const short8*)&pA[(wr * 64 + mi * 16 + (lane & 15)) * 64 + kk * 32 + (lane >> 4) * 8];
#pragma unroll
    for (int ni = 0; ni < 2; ++ni)
#pragma unroll
      for (int kk = 0; kk < 2; ++kk)
        bf[ni][kk] = *(const short8*)&pB[(wc * 32 + ni * 16 + (lane & 15)) * 64 + kk * 32 + (lane >> 4) * 8];
#pragma unroll
    for (int kk = 0; kk < 2; ++kk)
#pragma unroll
      for (int mi = 0; mi < 4; ++mi)
#pragma unroll
        for (int ni = 0; ni < 2; ++ni)
          acc[mi][ni] = __builtin_amdgcn_mfma_f32_16x16x32_bf16(af[mi][kk], bf[ni][kk], acc[mi][ni], 0, 0, 0);
    cur ^= 1;
  }
#undef STAGE

  const int lr = (lane >> 4) * 4, lc = lane & 15;
#pragma unroll
  for (int mi = 0; mi < 4; ++mi)
#pragma unroll
    for (int ni = 0; ni < 2; ++ni)
#pragma unroll
      for (int j = 0; j < 4; ++j) {
        const int m = bmr + wr * 64 + mi * 16 + lr + j;
        const int n = bnr + wc * 32 + ni * 16 + lc;
        if (EPI == 0) {
          atomicAdd(&dst[(size_t)n * MP + m], acc[mi][ni][j]);
        } else {
          if (m < N_NODES) atomicAdd(&dst[(size_t)m * OUT_C + n], acc[mi][ni][j]);
        }
      }
}

extern "C" void kernel_launch(void* const* d_in, const int* in_sizes, int n_in,
                              void* d_out, int out_size, void* d_ws, size_t ws_size,
                              hipStream_t stream) {
  const float* x    = (const float*)d_in[0];
  const int*   ei   = (const int*)d_in[1];
  const float* w    = (const float*)d_in[2];
  const float* bias = (const float*)d_in[3];
  float* out = (float*)d_out;

  char* ws = (char*)d_ws;
  u16*   xb  = (u16*)(ws + XB_OFF);
  u16*   wb  = (u16*)(ws + WB_OFF);
  u16*   hT  = (u16*)(ws + HT_OFF);
  float* hTf = (float*)(ws + HTF_OFF);
  u16*   Ac  = (u16*)(ws + AC_OFF);   // u16 counts, then bf16 in-place

  const int E = in_sizes[1] / 2;  // 500000

  // prep: x->bf16(padded), w->bf16, zero {hTf, Ac, out}
  k_prep<<<dim3(PREP_BLK), dim3(256), 0, stream>>>(x, w, xb, wb,
                                                   (float4*)hTf, (float4*)out);
  // edge counts (u16 halfword atomics)
  k_count<<<dim3((E + 255) / 256), dim3(256), 0, stream>>>(ei, (u32*)Ac, E);
  // counts -> bf16 in place
  k_cvtA<<<dim3((int)(AC_SZ / 16 + 255) / 256), dim3(256), 0, stream>>>(
      (uint4*)Ac, (int)(AC_SZ / 16));
  // GEMM1: hTf[n][m] += xb[m][k]*wb[n][k]   (K=2048, split 4 -> 704 blocks)
  k_gemm<IN_C, 8, 0><<<dim3(8 * 22 * 4), dim3(256), 0, stream>>>(xb, wb, hTf);
  // + bias, -> bf16 hT
  k_biascvt<<<dim3(OUT_C * MP / 8 / 256), dim3(256), 0, stream>>>(hTf, bias, hT);
  // GEMM2: out[m][n] += Ab[m][k]*hT[n][k]   (K=2816, split 4 -> 704 blocks)
  k_gemm<KP, 11, 1><<<dim3(8 * 22 * 4), dim3(256), 0, stream>>>(Ac, hT, out);
}

// Round 4
// 167.543 us; speedup vs baseline: 1.3529x; 1.3529x over previous
//
#include <hip/hip_runtime.h>
#include <stdint.h>

typedef unsigned short u16;
typedef unsigned int u32;

#define N_NODES 2708
#define IN_C    2048
#define OUT_C   512
#define MP      2816   // padded node count (multiple of 128)
#define KP      2816   // padded K for gemm2 (= MP)

using floatx4 = __attribute__((ext_vector_type(4))) float;
using short8  = __attribute__((ext_vector_type(8))) short;

// ---- workspace layout (32.4 MB total) ----
constexpr size_t XB_OFF = 0;
constexpr size_t XB_SZ  = (size_t)MP * IN_C * 2;      // 11,534,336
constexpr size_t WB_OFF = XB_OFF + XB_SZ;
constexpr size_t WB_SZ  = (size_t)OUT_C * IN_C * 2;   //  2,097,152
constexpr size_t HT_OFF = WB_OFF + WB_SZ;
constexpr size_t HT_SZ  = (size_t)OUT_C * MP * 2;     //  2,883,584
constexpr size_t AC_OFF = HT_OFF + HT_SZ;             // 16,515,072 (16B aligned)
constexpr size_t AC_SZ  = (size_t)MP * KP * 2;        // 15,859,712

static __device__ __forceinline__ u16 f2bf(float f) {
  union { float f; u32 u; } v; v.f = f;
  u32 r = v.u + 0x7fffu + ((v.u >> 16) & 1u);  // RNE
  return (u16)(r >> 16);
}

// ---- fused prep: x -> bf16 (padded rows), w -> bf16, zero Ac ----
constexpr int XBLK = MP * IN_C / 8 / 256;              // 2816 (block b == row b)
constexpr int WBLK = OUT_C * IN_C / 8 / 256;           // 512
constexpr int ZF4  = (int)(AC_SZ / 16);                // 991,232
constexpr int ZBLK = ZF4 / 256;                        // 3872 (exact)
constexpr int PREP_BLK = XBLK + WBLK + ZBLK;           // 7200

__global__ void k_prep(const float* __restrict__ x, const float* __restrict__ w,
                       u16* __restrict__ xb, u16* __restrict__ wb,
                       float4* __restrict__ zac) {
  const int b = blockIdx.x, tid = threadIdx.x;
  if (b < XBLK) {
    const int row = b, col = tid * 8;
    union { u16 u[8]; uint4 v; } o;
    if (row < N_NODES) {
      float4 v0 = *(const float4*)&x[(size_t)row * IN_C + col];
      float4 v1 = *(const float4*)&x[(size_t)row * IN_C + col + 4];
      o.u[0]=f2bf(v0.x); o.u[1]=f2bf(v0.y); o.u[2]=f2bf(v0.z); o.u[3]=f2bf(v0.w);
      o.u[4]=f2bf(v1.x); o.u[5]=f2bf(v1.y); o.u[6]=f2bf(v1.z); o.u[7]=f2bf(v1.w);
    } else {
      o.v = make_uint4(0, 0, 0, 0);
    }
    *(uint4*)&xb[(size_t)row * IN_C + col] = o.v;
  } else if (b < XBLK + WBLK) {
    const int idx = ((b - XBLK) * 256 + tid) * 8;
    float4 v0 = *(const float4*)&w[idx];
    float4 v1 = *(const float4*)&w[idx + 4];
    union { u16 u[8]; uint4 v; } o;
    o.u[0]=f2bf(v0.x); o.u[1]=f2bf(v0.y); o.u[2]=f2bf(v0.z); o.u[3]=f2bf(v0.w);
    o.u[4]=f2bf(v1.x); o.u[5]=f2bf(v1.y); o.u[6]=f2bf(v1.z); o.u[7]=f2bf(v1.w);
    *(uint4*)&wb[idx] = o.v;
  } else {
    const int i = (b - XBLK - WBLK) * 256 + tid;
    zac[i] = make_float4(0.f, 0.f, 0.f, 0.f);
  }
}

// ---- edge counts into u16 halfwords via u32 atomics ----
__global__ void k_count(const int* __restrict__ ei, u32* __restrict__ Ac, int E) {
  int e = blockIdx.x * 256 + threadIdx.x;
  if (e < E) {
    int src = ei[e];
    int dst = ei[E + e];
    u32 idx = (u32)dst * KP + (u32)src;  // u16 element index
    atomicAdd(&Ac[idx >> 1], 1u << ((idx & 1) * 16));
  }
}

// ---- in-place u16 count -> bf16 (exact for counts <= 256) ----
static __device__ __forceinline__ u32 cvt2(u32 w) {
  float lo = (float)(w & 0xffffu), hi = (float)(w >> 16);
  return (u32)f2bf(lo) | ((u32)f2bf(hi) << 16);
}
__global__ void k_cvtA(uint4* __restrict__ A, int n) {
  int i = blockIdx.x * 256 + threadIdx.x;
  if (i < n) {
    uint4 v = A[i];
    A[i] = make_uint4(cvt2(v.x), cvt2(v.y), cvt2(v.z), cvt2(v.w));
  }
}

// ---- GEMM: C[m][n] = sum_k A[m][k]*B[n][k] (+bias), bf16 row-major, ld=LDK.
// BM=128 BN=64 BK=64, 4 waves 2x2 (wave tile 64x32), full K per block (no split,
// no atomics). Double-buffered global_load_lds staging (T3-minimum 2-phase).
// T2 both-sides LDS swizzle (rule #21): linear LDS dest, global source slot
// pre-XOR'd by row&7, ds_read slot XOR'd by row&7 -> ~2-way conflicts (free).
// Grid = 176 (8 bn x 22 bm), XCD-bijective swizzle for A-panel L2 locality.
// EPI=0: dst = hT bf16 [OUT_C][MP], writes f2bf(acc + bias[n]) transposed.
// EPI=1: dst = out f32 [N_NODES][OUT_C], plain stores, m < N_NODES guard.
template<int LDK, int NKI, int EPI>
__global__ __launch_bounds__(256, 3) void k_gemm(
    const u16* __restrict__ A, const u16* __restrict__ B,
    const float* __restrict__ bias, void* __restrict__ dst) {
  __shared__ u16 lA[2][128 * 64];
  __shared__ u16 lB[2][64 * 64];
  const int tid = threadIdx.x, lane = tid & 63, wid = tid >> 6;

  // XCD swizzle (m157; gridDim.x == 176, 176 % 8 == 0 -> bijective)
  const int cpx = (int)gridDim.x >> 3;
  const int orig = blockIdx.x;
  const int swz = (orig & 7) * cpx + (orig >> 3);
  const int bn = swz & 7, bm = swz >> 3;
  const int bmr = bm * 128, bnr = bn * 64;

  const int wr = wid >> 1, wc = wid & 1;

  // staging: chunk c = 1024B = 8 tile rows; lane l -> row 8c+(l>>3),
  // 16B slot (l&7) XOR'd by row&7 = (l>>3)&7  (pre-swizzled global source)
  const int swzl = ((lane & 7) ^ ((lane >> 3) & 7)) * 16;
  const char* ag[4];
  const char* bg[2];
#pragma unroll
  for (int j = 0; j < 4; ++j) {
    int c = wid + 4 * j, row = 8 * c + (lane >> 3);
    ag[j] = (const char*)A + (size_t)(bmr + row) * (LDK * 2) + swzl;
  }
#pragma unroll
  for (int j = 0; j < 2; ++j) {
    int c = wid + 4 * j, row = 8 * c + (lane >> 3);
    bg[j] = (const char*)B + (size_t)(bnr + row) * (LDK * 2) + swzl;
  }

#define STAGE(bb, tt) do {                                                        \
  _Pragma("unroll")                                                               \
  for (int j = 0; j < 4; ++j)                                                     \
    __builtin_amdgcn_global_load_lds(                                             \
      (const __attribute__((address_space(1))) u32*)(ag[j] + (size_t)(tt) * 128), \
      (__attribute__((address_space(3))) u32*)&lA[bb][(wid + 4 * j) * 512],       \
      16, 0, 0);                                                                  \
  _Pragma("unroll")                                                               \
  for (int j = 0; j < 2; ++j)                                                     \
    __builtin_amdgcn_global_load_lds(                                             \
      (const __attribute__((address_space(1))) u32*)(bg[j] + (size_t)(tt) * 128), \
      (__attribute__((address_space(3))) u32*)&lB[bb][(wid + 4 * j) * 512],       \
      16, 0, 0);                                                                  \
} while (0)

  floatx4 acc[4][2] = {};

  STAGE(0, 0);
  int cur = 0;
  for (int t = 0; t < NKI; ++t) {
    __syncthreads();                         // stage(t) landed
    if (t + 1 < NKI) STAGE(cur ^ 1, t + 1);  // prefetch overlaps MFMA below
    const u16* pA = lA[cur];
    const u16* pB = lB[cur];
    short8 af[4][2], bf[2][2];
    // read-side swizzle: slot = kk*4 + (lane>>4), slot' = slot ^ (row&7),
    // row&7 == lane&7 for both A (row = wr*64+mi*16+(lane&15)) and B.
#pragma unroll
    for (int mi = 0; mi < 4; ++mi)
#pragma unroll
      for (int kk = 0; kk < 2; ++kk) {
        const int row = wr * 64 + mi * 16 + (lane & 15);
        const int col8 = ((kk * 4 + (lane >> 4)) ^ (lane & 7)) * 8;
        af[mi][kk] = *(const short8*)&pA[row * 64 + col8];
      }
#pragma unroll
    for (int ni = 0; ni < 2; ++ni)
#pragma unroll
      for (int kk = 0; kk < 2; ++kk) {
        const int row = wc * 32 + ni * 16 + (lane & 15);
        const int col8 = ((kk * 4 + (lane >> 4)) ^ (lane & 7)) * 8;
        bf[ni][kk] = *(const short8*)&pB[row * 64 + col8];
      }
#pragma unroll
    for (int kk = 0; kk < 2; ++kk)
#pragma unroll
      for (int mi = 0; mi < 4; ++mi)
#pragma unroll
        for (int ni = 0; ni < 2; ++ni)
          acc[mi][ni] = __builtin_amdgcn_mfma_f32_16x16x32_bf16(af[mi][kk], bf[ni][kk], acc[mi][ni], 0, 0, 0);
    cur ^= 1;
  }
#undef STAGE

  const int lr = (lane >> 4) * 4, lc = lane & 15;
  if (EPI == 0) {
    u16* hTp = (u16*)dst;
#pragma unroll
    for (int ni = 0; ni < 2; ++ni) {
      const int n = bnr + wc * 32 + ni * 16 + lc;
      const float bv = bias[n];
#pragma unroll
      for (int mi = 0; mi < 4; ++mi) {
        const int m0 = bmr + wr * 64 + mi * 16 + lr;
        union { u16 u[4]; uint2 v; } o;
#pragma unroll
        for (int j = 0; j < 4; ++j) o.u[j] = f2bf(acc[mi][ni][j] + bv);
        *(uint2*)&hTp[(size_t)n * MP + m0] = o.v;
      }
    }
  } else {
    float* op = (float*)dst;
#pragma unroll
    for (int mi = 0; mi < 4; ++mi)
#pragma unroll
      for (int j = 0; j < 4; ++j) {
        const int m = bmr + wr * 64 + mi * 16 + lr + j;
        if (m < N_NODES) {
#pragma unroll
          for (int ni = 0; ni < 2; ++ni) {
            const int n = bnr + wc * 32 + ni * 16 + lc;
            op[(size_t)m * OUT_C + n] = acc[mi][ni][j];
          }
        }
      }
  }
}

extern "C" void kernel_launch(void* const* d_in, const int* in_sizes, int n_in,
                              void* d_out, int out_size, void* d_ws, size_t ws_size,
                              hipStream_t stream) {
  const float* x    = (const float*)d_in[0];
  const int*   ei   = (const int*)d_in[1];
  const float* w    = (const float*)d_in[2];
  const float* bias = (const float*)d_in[3];
  float* out = (float*)d_out;

  char* ws = (char*)d_ws;
  u16* xb = (u16*)(ws + XB_OFF);
  u16* wb = (u16*)(ws + WB_OFF);
  u16* hT = (u16*)(ws + HT_OFF);
  u16* Ac = (u16*)(ws + AC_OFF);   // u16 counts, then bf16 in-place

  const int E = in_sizes[1] / 2;  // 500000

  // prep: x->bf16(padded), w->bf16, zero Ac
  k_prep<<<dim3(PREP_BLK), dim3(256), 0, stream>>>(x, w, xb, wb, (float4*)Ac);
  // edge counts (u16 halfword atomics)
  k_count<<<dim3((E + 255) / 256), dim3(256), 0, stream>>>(ei, (u32*)Ac, E);
  // counts -> bf16 in place
  k_cvtA<<<dim3(ZF4 / 256), dim3(256), 0, stream>>>((uint4*)Ac, ZF4);
  // GEMM1: hT[n][m] = bf16(sum_k xb[m][k]*wb[n][k] + bias[n])   (K=2048)
  k_gemm<IN_C, IN_C / 64, 0><<<dim3(176), dim3(256), 0, stream>>>(xb, wb, bias, hT);
  // GEMM2: out[m][n] = sum_k Ac[m][k]*hT[n][k]   (K=2816)
  k_gemm<KP, KP / 64, 1><<<dim3(176), dim3(256), 0, stream>>>(Ac, hT, bias, out);
}

// Round 5
// 155.591 us; speedup vs baseline: 1.4568x; 1.0768x over previous
//
#include <hip/hip_runtime.h>
#include <stdint.h>

typedef unsigned short u16;
typedef unsigned int u32;

#define N_NODES 2708
#define IN_C    2048
#define OUT_C   512
#define MP      2816   // padded node count (multiple of 128)
#define KP      2816   // padded K for gemm2 (= MP)

using floatx4 = __attribute__((ext_vector_type(4))) float;
using short8  = __attribute__((ext_vector_type(8))) short;

// ---- workspace layout (32.4 MB total) ----
constexpr size_t XB_OFF = 0;
constexpr size_t XB_SZ  = (size_t)MP * IN_C * 2;      // 11,534,336
constexpr size_t WB_OFF = XB_OFF + XB_SZ;
constexpr size_t WB_SZ  = (size_t)OUT_C * IN_C * 2;   //  2,097,152
constexpr size_t HT_OFF = WB_OFF + WB_SZ;
constexpr size_t HT_SZ  = (size_t)OUT_C * MP * 2;     //  2,883,584
constexpr size_t AC_OFF = HT_OFF + HT_SZ;             // 16,515,072 (16B aligned)
constexpr size_t AC_SZ  = (size_t)MP * KP * 2;        // 15,859,712

static __device__ __forceinline__ u16 f2bf(float f) {
  union { float f; u32 u; } v; v.f = f;
  u32 r = v.u + 0x7fffu + ((v.u >> 16) & 1u);  // RNE
  return (u16)(r >> 16);
}

// ---- fused prep: x -> bf16 (padded rows), w -> bf16, zero Ac ----
constexpr int XBLK = MP * IN_C / 8 / 256;              // 2816 (block b == row b)
constexpr int WBLK = OUT_C * IN_C / 8 / 256;           // 512
constexpr int ZF4  = (int)(AC_SZ / 16);                // 991,232
constexpr int ZBLK = ZF4 / 256;                        // 3872 (exact)
constexpr int PREP_BLK = XBLK + WBLK + ZBLK;           // 7200

__global__ void k_prep(const float* __restrict__ x, const float* __restrict__ w,
                       u16* __restrict__ xb, u16* __restrict__ wb,
                       float4* __restrict__ zac) {
  const int b = blockIdx.x, tid = threadIdx.x;
  if (b < XBLK) {
    const int row = b, col = tid * 8;
    union { u16 u[8]; uint4 v; } o;
    if (row < N_NODES) {
      float4 v0 = *(const float4*)&x[(size_t)row * IN_C + col];
      float4 v1 = *(const float4*)&x[(size_t)row * IN_C + col + 4];
      o.u[0]=f2bf(v0.x); o.u[1]=f2bf(v0.y); o.u[2]=f2bf(v0.z); o.u[3]=f2bf(v0.w);
      o.u[4]=f2bf(v1.x); o.u[5]=f2bf(v1.y); o.u[6]=f2bf(v1.z); o.u[7]=f2bf(v1.w);
    } else {
      o.v = make_uint4(0, 0, 0, 0);
    }
    *(uint4*)&xb[(size_t)row * IN_C + col] = o.v;
  } else if (b < XBLK + WBLK) {
    const int idx = ((b - XBLK) * 256 + tid) * 8;
    float4 v0 = *(const float4*)&w[idx];
    float4 v1 = *(const float4*)&w[idx + 4];
    union { u16 u[8]; uint4 v; } o;
    o.u[0]=f2bf(v0.x); o.u[1]=f2bf(v0.y); o.u[2]=f2bf(v0.z); o.u[3]=f2bf(v0.w);
    o.u[4]=f2bf(v1.x); o.u[5]=f2bf(v1.y); o.u[6]=f2bf(v1.z); o.u[7]=f2bf(v1.w);
    *(uint4*)&wb[idx] = o.v;
  } else {
    const int i = (b - XBLK - WBLK) * 256 + tid;
    zac[i] = make_float4(0.f, 0.f, 0.f, 0.f);
  }
}

// ---- edge counts into u16 halfwords via u32 atomics ----
__global__ void k_count(const int* __restrict__ ei, u32* __restrict__ Ac, int E) {
  int e = blockIdx.x * 256 + threadIdx.x;
  if (e < E) {
    int src = ei[e];
    int dst = ei[E + e];
    u32 idx = (u32)dst * KP + (u32)src;  // u16 element index
    atomicAdd(&Ac[idx >> 1], 1u << ((idx & 1) * 16));
  }
}

// ---- in-place u16 count -> bf16 (exact for counts <= 256) ----
static __device__ __forceinline__ u32 cvt2(u32 w) {
  float lo = (float)(w & 0xffffu), hi = (float)(w >> 16);
  return (u32)f2bf(lo) | ((u32)f2bf(hi) << 16);
}
__global__ void k_cvtA(uint4* __restrict__ A, int n) {
  int i = blockIdx.x * 256 + threadIdx.x;
  if (i < n) {
    uint4 v = A[i];
    A[i] = make_uint4(cvt2(v.x), cvt2(v.y), cvt2(v.z), cvt2(v.w));
  }
}

// ---- GEMM: C[m][n] = sum_k A[m][k]*B[n][k] (+bias), bf16 row-major, ld=LDK.
// BM=64 BN=32 BK=64, 4 waves 2x2 (wave tile 32x16). Grid 44x16 = 704 blocks
// (2.75/CU -> inter-block latency overlap; R4's 176 = 1/CU was the bottleneck).
// Double-buffered global_load_lds (2-phase), T2 both-sides swizzle (rule #21),
// XCD-bijective block swizzle (704 % 8 == 0).
// EPI=0: dst = hT bf16 [OUT_C][MP], writes f2bf(acc + bias[n]) transposed.
// EPI=1: dst = out f32 [N_NODES][OUT_C], plain stores, m < N_NODES guard.
template<int LDK, int NKI, int EPI>
__global__ __launch_bounds__(256, 4) void k_gemm(
    const u16* __restrict__ A, const u16* __restrict__ B,
    const float* __restrict__ bias, void* __restrict__ dst) {
  __shared__ u16 lA[2][64 * 64];
  __shared__ u16 lB[2][32 * 64];
  const int tid = threadIdx.x, lane = tid & 63, wid = tid >> 6;

  // XCD swizzle: consecutive-origs (same XCD) -> consecutive swz -> same bm
  // neighborhood; per-XCD working set ~A 5.5 panels + full B (~3.4-4.8 MB).
  const int cpx = (int)gridDim.x >> 3;          // 88
  const int orig = blockIdx.x;
  const int swz = (orig & 7) * cpx + (orig >> 3);
  const int bn = swz & 15, bm = swz >> 4;
  const int bmr = bm * 64, bnr = bn * 32;

  const int wr = wid >> 1, wc = wid & 1;

  // staging: chunk c = 1024B = 8 tile rows; lane l -> row 8c+(l>>3),
  // 16B slot (l&7) XOR'd by row&7 = (l>>3) (pre-swizzled global source).
  // A: 8 chunks (wave w -> {w, w+4}); B: 4 chunks (wave w -> {w}).
  const int swzl = ((lane & 7) ^ ((lane >> 3) & 7)) * 16;
  const char* ag[2];
  const char* bg1;
#pragma unroll
  for (int j = 0; j < 2; ++j) {
    int c = wid + 4 * j, row = 8 * c + (lane >> 3);
    ag[j] = (const char*)A + (size_t)(bmr + row) * (LDK * 2) + swzl;
  }
  {
    int row = 8 * wid + (lane >> 3);
    bg1 = (const char*)B + (size_t)(bnr + row) * (LDK * 2) + swzl;
  }

#define STAGE(bb, tt) do {                                                        \
  _Pragma("unroll")                                                               \
  for (int j = 0; j < 2; ++j)                                                     \
    __builtin_amdgcn_global_load_lds(                                             \
      (const __attribute__((address_space(1))) u32*)(ag[j] + (size_t)(tt) * 128), \
      (__attribute__((address_space(3))) u32*)&lA[bb][(wid + 4 * j) * 512],       \
      16, 0, 0);                                                                  \
  __builtin_amdgcn_global_load_lds(                                               \
      (const __attribute__((address_space(1))) u32*)(bg1 + (size_t)(tt) * 128),   \
      (__attribute__((address_space(3))) u32*)&lB[bb][wid * 512],                 \
      16, 0, 0);                                                                  \
} while (0)

  floatx4 acc[2] = {};

  STAGE(0, 0);
  int cur = 0;
  for (int t = 0; t < NKI; ++t) {
    __syncthreads();                         // stage(t) landed
    if (t + 1 < NKI) STAGE(cur ^ 1, t + 1);  // prefetch overlaps MFMA below
    const u16* pA = lA[cur];
    const u16* pB = lB[cur];
    short8 af[2][2], bf[2];
    // read-side swizzle: slot' = slot ^ (row&7); row&7 == lane&7 for A and B.
#pragma unroll
    for (int mi = 0; mi < 2; ++mi)
#pragma unroll
      for (int kk = 0; kk < 2; ++kk) {
        const int row = wr * 32 + mi * 16 + (lane & 15);
        const int col8 = ((kk * 4 + (lane >> 4)) ^ (lane & 7)) * 8;
        af[mi][kk] = *(const short8*)&pA[row * 64 + col8];
      }
#pragma unroll
    for (int kk = 0; kk < 2; ++kk) {
      const int row = wc * 16 + (lane & 15);
      const int col8 = ((kk * 4 + (lane >> 4)) ^ (lane & 7)) * 8;
      bf[kk] = *(const short8*)&pB[row * 64 + col8];
    }
#pragma unroll
    for (int kk = 0; kk < 2; ++kk)
#pragma unroll
      for (int mi = 0; mi < 2; ++mi)
        acc[mi] = __builtin_amdgcn_mfma_f32_16x16x32_bf16(af[mi][kk], bf[kk], acc[mi], 0, 0, 0);
    cur ^= 1;
  }
#undef STAGE

  const int lr = (lane >> 4) * 4, lc = lane & 15;
  if (EPI == 0) {
    u16* hTp = (u16*)dst;
    const int n = bnr + wc * 16 + lc;
    const float bv = bias[n];
#pragma unroll
    for (int mi = 0; mi < 2; ++mi) {
      const int m0 = bmr + wr * 32 + mi * 16 + lr;
      union { u16 u[4]; uint2 v; } o;
#pragma unroll
      for (int j = 0; j < 4; ++j) o.u[j] = f2bf(acc[mi][j] + bv);
      *(uint2*)&hTp[(size_t)n * MP + m0] = o.v;
    }
  } else {
    float* op = (float*)dst;
    const int n = bnr + wc * 16 + lc;
#pragma unroll
    for (int mi = 0; mi < 2; ++mi)
#pragma unroll
      for (int j = 0; j < 4; ++j) {
        const int m = bmr + wr * 32 + mi * 16 + lr + j;
        if (m < N_NODES) op[(size_t)m * OUT_C + n] = acc[mi][j];
      }
  }
}

extern "C" void kernel_launch(void* const* d_in, const int* in_sizes, int n_in,
                              void* d_out, int out_size, void* d_ws, size_t ws_size,
                              hipStream_t stream) {
  const float* x    = (const float*)d_in[0];
  const int*   ei   = (const int*)d_in[1];
  const float* w    = (const float*)d_in[2];
  const float* bias = (const float*)d_in[3];
  float* out = (float*)d_out;

  char* ws = (char*)d_ws;
  u16* xb = (u16*)(ws + XB_OFF);
  u16* wb = (u16*)(ws + WB_OFF);
  u16* hT = (u16*)(ws + HT_OFF);
  u16* Ac = (u16*)(ws + AC_OFF);   // u16 counts, then bf16 in-place

  const int E = in_sizes[1] / 2;  // 500000

  // prep: x->bf16(padded), w->bf16, zero Ac
  k_prep<<<dim3(PREP_BLK), dim3(256), 0, stream>>>(x, w, xb, wb, (float4*)Ac);
  // edge counts (u16 halfword atomics)
  k_count<<<dim3((E + 255) / 256), dim3(256), 0, stream>>>(ei, (u32*)Ac, E);
  // counts -> bf16 in place
  k_cvtA<<<dim3(ZF4 / 256), dim3(256), 0, stream>>>((uint4*)Ac, ZF4);
  // GEMM1: hT[n][m] = bf16(sum_k xb[m][k]*wb[n][k] + bias[n])   (K=2048)
  k_gemm<IN_C, IN_C / 64, 0><<<dim3(704), dim3(256), 0, stream>>>(xb, wb, bias, hT);
  // GEMM2: out[m][n] = sum_k Ac[m][k]*hT[n][k]   (K=2816)
  k_gemm<KP, KP / 64, 1><<<dim3(704), dim3(256), 0, stream>>>(Ac, hT, bias, out);
}

// Round 6
// 149.533 us; speedup vs baseline: 1.5158x; 1.0405x over previous
//
#include <hip/hip_runtime.h>
#include <stdint.h>

typedef unsigned short u16;
typedef unsigned int u32;

#define N_NODES 2708
#define IN_C    2048
#define OUT_C   512
#define MP      2816   // padded node count (multiple of 128)
#define KP      2816   // padded K for gemm2 (= MP)

using floatx4 = __attribute__((ext_vector_type(4))) float;
using short8  = __attribute__((ext_vector_type(8))) short;

// ---- workspace layout (32.4 MB total) ----
constexpr size_t XB_OFF = 0;
constexpr size_t XB_SZ  = (size_t)MP * IN_C * 2;      // 11,534,336
constexpr size_t WB_OFF = XB_OFF + XB_SZ;
constexpr size_t WB_SZ  = (size_t)OUT_C * IN_C * 2;   //  2,097,152
constexpr size_t HT_OFF = WB_OFF + WB_SZ;
constexpr size_t HT_SZ  = (size_t)OUT_C * MP * 2;     //  2,883,584
constexpr size_t AC_OFF = HT_OFF + HT_SZ;             // 16,515,072 (16B aligned)
constexpr size_t AC_SZ  = (size_t)MP * KP * 2;        // 15,859,712

static __device__ __forceinline__ u16 f2bf(float f) {
  union { float f; u32 u; } v; v.f = f;
  u32 r = v.u + 0x7fffu + ((v.u >> 16) & 1u);  // RNE
  return (u16)(r >> 16);
}

// ---- fused prep: x -> bf16 (padded rows), w -> bf16, zero Ac ----
constexpr int XBLK = MP * IN_C / 8 / 256;              // 2816 (block b == row b)
constexpr int WBLK = OUT_C * IN_C / 8 / 256;           // 512
constexpr int ZF4  = (int)(AC_SZ / 16);                // 991,232
constexpr int ZBLK = ZF4 / 256;                        // 3872 (exact)
constexpr int PREP_BLK = XBLK + WBLK + ZBLK;           // 7200

__global__ void k_prep(const float* __restrict__ x, const float* __restrict__ w,
                       u16* __restrict__ xb, u16* __restrict__ wb,
                       float4* __restrict__ zac) {
  const int b = blockIdx.x, tid = threadIdx.x;
  if (b < XBLK) {
    const int row = b, col = tid * 8;
    union { u16 u[8]; uint4 v; } o;
    if (row < N_NODES) {
      float4 v0 = *(const float4*)&x[(size_t)row * IN_C + col];
      float4 v1 = *(const float4*)&x[(size_t)row * IN_C + col + 4];
      o.u[0]=f2bf(v0.x); o.u[1]=f2bf(v0.y); o.u[2]=f2bf(v0.z); o.u[3]=f2bf(v0.w);
      o.u[4]=f2bf(v1.x); o.u[5]=f2bf(v1.y); o.u[6]=f2bf(v1.z); o.u[7]=f2bf(v1.w);
    } else {
      o.v = make_uint4(0, 0, 0, 0);
    }
    *(uint4*)&xb[(size_t)row * IN_C + col] = o.v;
  } else if (b < XBLK + WBLK) {
    const int idx = ((b - XBLK) * 256 + tid) * 8;
    float4 v0 = *(const float4*)&w[idx];
    float4 v1 = *(const float4*)&w[idx + 4];
    union { u16 u[8]; uint4 v; } o;
    o.u[0]=f2bf(v0.x); o.u[1]=f2bf(v0.y); o.u[2]=f2bf(v0.z); o.u[3]=f2bf(v0.w);
    o.u[4]=f2bf(v1.x); o.u[5]=f2bf(v1.y); o.u[6]=f2bf(v1.z); o.u[7]=f2bf(v1.w);
    *(uint4*)&wb[idx] = o.v;
  } else {
    const int i = (b - XBLK - WBLK) * 256 + tid;
    zac[i] = make_float4(0.f, 0.f, 0.f, 0.f);
  }
}

// ---- edge counts into u16 halfwords via u32 atomics ----
__global__ void k_count(const int* __restrict__ ei, u32* __restrict__ Ac, int E) {
  int e = blockIdx.x * 256 + threadIdx.x;
  if (e < E) {
    int src = ei[e];
    int dst = ei[E + e];
    u32 idx = (u32)dst * KP + (u32)src;  // u16 element index
    atomicAdd(&Ac[idx >> 1], 1u << ((idx & 1) * 16));
  }
}

// ---- in-place u16 count -> bf16 (exact for counts <= 256) ----
static __device__ __forceinline__ u32 cvt2(u32 w) {
  float lo = (float)(w & 0xffffu), hi = (float)(w >> 16);
  return (u32)f2bf(lo) | ((u32)f2bf(hi) << 16);
}
__global__ void k_cvtA(uint4* __restrict__ A, int n) {
  int i = blockIdx.x * 256 + threadIdx.x;
  if (i < n) {
    uint4 v = A[i];
    A[i] = make_uint4(cvt2(v.x), cvt2(v.y), cvt2(v.z), cvt2(v.w));
  }
}

// ---- GEMM: C[m][n] = sum_k A[m][k]*B[n][k] (+bias), bf16 row-major, ld=LDK.
// BM=64 BN=32 BK=64, 4 waves 2x2 (wave tile 32x16), grid 704 (2.75/CU).
// T4 counted-vmcnt pipeline: 3 LDS buffers, STAGE issued 2 iterations ahead,
// s_waitcnt vmcnt(3) (never 0 mid-loop) + raw s_barrier -> prefetch stays in
// flight across barriers (the R5 __syncthreads drained vmcnt(0) every iter,
// serializing on full L2/L3 latency). T2 both-sides swizzle (rule #21),
// XCD-bijective block swizzle (704 % 8 == 0). T5 setprio around MFMA.
// EPI=0: dst = hT bf16 [OUT_C][MP], writes f2bf(acc + bias[n]) transposed.
// EPI=1: dst = out f32 [N_NODES][OUT_C], plain stores, m < N_NODES guard.
template<int LDK, int NKI, int EPI>
__global__ __launch_bounds__(256, 4) void k_gemm(
    const u16* __restrict__ A, const u16* __restrict__ B,
    const float* __restrict__ bias, void* __restrict__ dst) {
  __shared__ u16 lA[3][64 * 64];
  __shared__ u16 lB[3][32 * 64];
  const int tid = threadIdx.x, lane = tid & 63, wid = tid >> 6;

  // XCD swizzle: consecutive-origs (same XCD) -> consecutive swz -> same bm
  // neighborhood; per-XCD working set ~A-slice + full B panel.
  const int cpx = (int)gridDim.x >> 3;          // 88
  const int orig = blockIdx.x;
  const int swz = (orig & 7) * cpx + (orig >> 3);
  const int bn = swz & 15, bm = swz >> 4;
  const int bmr = bm * 64, bnr = bn * 32;

  const int wr = wid >> 1, wc = wid & 1;

  // staging: chunk c = 1024B = 8 tile rows; lane l -> row 8c+(l>>3),
  // 16B slot (l&7) XOR'd by row&7 = (l>>3) (pre-swizzled global source).
  const int swzl = ((lane & 7) ^ ((lane >> 3) & 7)) * 16;
  const char* ag[2];
  const char* bg1;
#pragma unroll
  for (int j = 0; j < 2; ++j) {
    int c = wid + 4 * j, row = 8 * c + (lane >> 3);
    ag[j] = (const char*)A + (size_t)(bmr + row) * (LDK * 2) + swzl;
  }
  {
    int row = 8 * wid + (lane >> 3);
    bg1 = (const char*)B + (size_t)(bnr + row) * (LDK * 2) + swzl;
  }

  // 3 global_load_lds per thread per STAGE (2 A + 1 B) -> vmcnt units of 3
#define STAGE(bb, tt) do {                                                        \
  _Pragma("unroll")                                                               \
  for (int j = 0; j < 2; ++j)                                                     \
    __builtin_amdgcn_global_load_lds(                                             \
      (const __attribute__((address_space(1))) u32*)(ag[j] + (size_t)(tt) * 128), \
      (__attribute__((address_space(3))) u32*)&lA[bb][(wid + 4 * j) * 512],       \
      16, 0, 0);                                                                  \
  __builtin_amdgcn_global_load_lds(                                               \
      (const __attribute__((address_space(1))) u32*)(bg1 + (size_t)(tt) * 128),   \
      (__attribute__((address_space(3))) u32*)&lB[bb][wid * 512],                 \
      16, 0, 0);                                                                  \
} while (0)

  floatx4 acc[2] = {};

  STAGE(0, 0);
  if (NKI > 1) STAGE(1, 1);
  int cur = 0;
  for (int t = 0; t < NKI; ++t) {
    // wait for stage(t) only: leaves stage(t+1)'s 3 loads in flight
    if (t + 1 < NKI) asm volatile("s_waitcnt vmcnt(3)" ::: "memory");
    else             asm volatile("s_waitcnt vmcnt(0)" ::: "memory");
    __builtin_amdgcn_s_barrier();
    asm volatile("" ::: "memory");           // fence: keep ds_reads below barrier
    if (t + 2 < NKI) {
      int nb = cur + 2; if (nb >= 3) nb -= 3;
      STAGE(nb, t + 2);                      // overwrites buf consumed at t-1: safe
    }
    const u16* pA = lA[cur];
    const u16* pB = lB[cur];
    short8 af[2][2], bf[2];
    // read-side swizzle: slot' = slot ^ (row&7); row&7 == lane&7 for A and B.
#pragma unroll
    for (int mi = 0; mi < 2; ++mi)
#pragma unroll
      for (int kk = 0; kk < 2; ++kk) {
        const int row = wr * 32 + mi * 16 + (lane & 15);
        const int col8 = ((kk * 4 + (lane >> 4)) ^ (lane & 7)) * 8;
        af[mi][kk] = *(const short8*)&pA[row * 64 + col8];
      }
#pragma unroll
    for (int kk = 0; kk < 2; ++kk) {
      const int row = wc * 16 + (lane & 15);
      const int col8 = ((kk * 4 + (lane >> 4)) ^ (lane & 7)) * 8;
      bf[kk] = *(const short8*)&pB[row * 64 + col8];
    }
    __builtin_amdgcn_s_setprio(1);
#pragma unroll
    for (int kk = 0; kk < 2; ++kk)
#pragma unroll
      for (int mi = 0; mi < 2; ++mi)
        acc[mi] = __builtin_amdgcn_mfma_f32_16x16x32_bf16(af[mi][kk], bf[kk], acc[mi], 0, 0, 0);
    __builtin_amdgcn_s_setprio(0);
    ++cur; if (cur >= 3) cur -= 3;
  }
#undef STAGE

  const int lr = (lane >> 4) * 4, lc = lane & 15;
  if (EPI == 0) {
    u16* hTp = (u16*)dst;
    const int n = bnr + wc * 16 + lc;
    const float bv = bias[n];
#pragma unroll
    for (int mi = 0; mi < 2; ++mi) {
      const int m0 = bmr + wr * 32 + mi * 16 + lr;
      union { u16 u[4]; uint2 v; } o;
#pragma unroll
      for (int j = 0; j < 4; ++j) o.u[j] = f2bf(acc[mi][j] + bv);
      *(uint2*)&hTp[(size_t)n * MP + m0] = o.v;
    }
  } else {
    float* op = (float*)dst;
    const int n = bnr + wc * 16 + lc;
#pragma unroll
    for (int mi = 0; mi < 2; ++mi)
#pragma unroll
      for (int j = 0; j < 4; ++j) {
        const int m = bmr + wr * 32 + mi * 16 + lr + j;
        if (m < N_NODES) op[(size_t)m * OUT_C + n] = acc[mi][j];
      }
  }
}

extern "C" void kernel_launch(void* const* d_in, const int* in_sizes, int n_in,
                              void* d_out, int out_size, void* d_ws, size_t ws_size,
                              hipStream_t stream) {
  const float* x    = (const float*)d_in[0];
  const int*   ei   = (const int*)d_in[1];
  const float* w    = (const float*)d_in[2];
  const float* bias = (const float*)d_in[3];
  float* out = (float*)d_out;

  char* ws = (char*)d_ws;
  u16* xb = (u16*)(ws + XB_OFF);
  u16* wb = (u16*)(ws + WB_OFF);
  u16* hT = (u16*)(ws + HT_OFF);
  u16* Ac = (u16*)(ws + AC_OFF);   // u16 counts, then bf16 in-place

  const int E = in_sizes[1] / 2;  // 500000

  // prep: x->bf16(padded), w->bf16, zero Ac
  k_prep<<<dim3(PREP_BLK), dim3(256), 0, stream>>>(x, w, xb, wb, (float4*)Ac);
  // edge counts (u16 halfword atomics)
  k_count<<<dim3((E + 255) / 256), dim3(256), 0, stream>>>(ei, (u32*)Ac, E);
  // counts -> bf16 in place
  k_cvtA<<<dim3(ZF4 / 256), dim3(256), 0, stream>>>((uint4*)Ac, ZF4);
  // GEMM1: hT[n][m] = bf16(sum_k xb[m][k]*wb[n][k] + bias[n])   (K=2048)
  k_gemm<IN_C, IN_C / 64, 0><<<dim3(704), dim3(256), 0, stream>>>(xb, wb, bias, hT);
  // GEMM2: out[m][n] = sum_k Ac[m][k]*hT[n][k]   (K=2816)
  k_gemm<KP, KP / 64, 1><<<dim3(704), dim3(256), 0, stream>>>(Ac, hT, bias, out);
}